// Round 1
// 940.456 us; speedup vs baseline: 1.0532x; 1.0532x over previous
//
#include <hip/hip_runtime.h>
#include <math.h>

#define D 256
#define NSEG 8192

typedef float f4_t __attribute__((ext_vector_type(4)));

// ---------- setup: segment starts (replaces per-block binary search) ----------
__global__ __launch_bounds__(256) void seg_starts_kernel(
        const int* __restrict__ obj, int T, int* __restrict__ starts) {
    const int i = blockIdx.x * blockDim.x + threadIdx.x;
    if (i >= T) return;
    const int cur  = obj[i];
    const int prev = (i == 0) ? -1 : obj[i - 1];
    for (int s = prev + 1; s <= cur; ++s) starts[s] = i;   // fills gaps (empty segs)
    if (i == T - 1) {
        for (int s = cur + 1; s <= NSEG; ++s) starts[s] = T;
    }
}

__device__ __forceinline__ int lower_bound_dev(const int* __restrict__ a, int n, int key) {
    int lo = 0, hi = n;
    while (lo < hi) {
        int mid = (lo + hi) >> 1;
        if (a[mid] < key) lo = mid + 1; else hi = mid;
    }
    return lo;
}

__device__ __forceinline__ float dot4(const float4 a, const float4 b) {
    return a.x * b.x + a.y * b.y + a.z * b.z + a.w * b.w;
}

// One block (256 threads = 4 waves) per segment. Fully fused:
//   pass 1: segment sum of emb rows (HBM read, coalesced float4, 2 loads in flight)
//   proj  : tg = tanh((s @ W) / cnt)   -- W stays L2-resident across blocks
//   pass 2: re-read same rows (L2-hot), score = sigmoid(row . tg), rep += row*score
//   pass 3: broadcast rep to every row (nontemporal: out is never re-read)
template <bool USE_STARTS>
__global__ __launch_bounds__(256) void fused_seg_kernel(
        const float* __restrict__ emb,
        const float* __restrict__ W,
        const int*   __restrict__ obj, int T,
        const int*   __restrict__ starts,
        float* __restrict__ out) {
    const int seg = blockIdx.x;
    int start, end;
    if (USE_STARTS) {
        start = starts[seg];          // uniform -> scalar loads
        end   = starts[seg + 1];
    } else {
        start = lower_bound_dev(obj, T, seg);
        end   = lower_bound_dev(obj, T, seg + 1);
    }
    if (start >= end) return;   // empty segment: no tokens reference it

    const int tid  = threadIdx.x;
    const int lane = tid & 63;
    const int w    = tid >> 6;

    __shared__ float sm[4][D];   // cross-wave reduction scratch
    __shared__ float sv[D];      // segment sum
    __shared__ float tg[D];      // transformed global context

    const size_t col = (size_t)(lane * 4);

    // ---- pass 1: segment sum (manual 2x unroll: two loads in flight) ----
    float4 acc = make_float4(0.f, 0.f, 0.f, 0.f);
    {
        int r = start + w;
        for (; r + 4 < end; r += 8) {
            const float4 e0 = *reinterpret_cast<const float4*>(emb + (size_t)r * D + col);
            const float4 e1 = *reinterpret_cast<const float4*>(emb + (size_t)(r + 4) * D + col);
            acc.x += e0.x + e1.x; acc.y += e0.y + e1.y;
            acc.z += e0.z + e1.z; acc.w += e0.w + e1.w;
        }
        if (r < end) {
            const float4 e0 = *reinterpret_cast<const float4*>(emb + (size_t)r * D + col);
            acc.x += e0.x; acc.y += e0.y; acc.z += e0.z; acc.w += e0.w;
        }
    }
    *reinterpret_cast<float4*>(&sm[w][lane * 4]) = acc;
    __syncthreads();
    sv[tid] = sm[0][tid] + sm[1][tid] + sm[2][tid] + sm[3][tid];
    __syncthreads();

    // ---- projection: thread tid owns column j=tid of W ----
    // per-k reads are 256 consecutive floats (coalesced); W (256 KB) is L2-hot.
    const float inv = 1.0f / (float)(end - start);
    float p = 0.f;
    #pragma unroll 16
    for (int k = 0; k < D; ++k) {
        p += sv[k] * W[k * D + tid];
    }
    tg[tid] = tanhf(p * inv);
    __syncthreads();
    const float4 tg4 = *reinterpret_cast<const float4*>(&tg[lane * 4]);

    // ---- pass 2: score + weighted sum (rows are L2-hot from pass 1) ----
    float4 racc = make_float4(0.f, 0.f, 0.f, 0.f);
    {
        int r = start + w;
        for (; r + 4 < end; r += 8) {
            const float4 e0 = *reinterpret_cast<const float4*>(emb + (size_t)r * D + col);
            const float4 e1 = *reinterpret_cast<const float4*>(emb + (size_t)(r + 4) * D + col);
            float pd0 = dot4(e0, tg4);
            float pd1 = dot4(e1, tg4);
            #pragma unroll
            for (int off = 32; off >= 1; off >>= 1) {
                pd0 += __shfl_xor(pd0, off, 64);
                pd1 += __shfl_xor(pd1, off, 64);
            }
            const float s0 = 1.0f / (1.0f + __expf(-pd0));
            const float s1 = 1.0f / (1.0f + __expf(-pd1));
            racc.x += e0.x * s0 + e1.x * s1;
            racc.y += e0.y * s0 + e1.y * s1;
            racc.z += e0.z * s0 + e1.z * s1;
            racc.w += e0.w * s0 + e1.w * s1;
        }
        if (r < end) {
            const float4 e0 = *reinterpret_cast<const float4*>(emb + (size_t)r * D + col);
            float pd0 = dot4(e0, tg4);
            #pragma unroll
            for (int off = 32; off >= 1; off >>= 1) pd0 += __shfl_xor(pd0, off, 64);
            const float s0 = 1.0f / (1.0f + __expf(-pd0));
            racc.x += e0.x * s0; racc.y += e0.y * s0;
            racc.z += e0.z * s0; racc.w += e0.w * s0;
        }
    }
    *reinterpret_cast<float4*>(&sm[w][lane * 4]) = racc;
    __syncthreads();
    sm[0][tid] = sm[0][tid] + sm[1][tid] + sm[2][tid] + sm[3][tid];
    __syncthreads();
    const float4 rep4 = *reinterpret_cast<const float4*>(&sm[0][lane * 4]);
    const f4_t repv = { rep4.x, rep4.y, rep4.z, rep4.w };

    // ---- pass 3: broadcast rep to every token row (nontemporal stores) ----
    {
        int r = start + w;
        for (; r + 4 < end; r += 8) {
            __builtin_nontemporal_store(repv, reinterpret_cast<f4_t*>(out + (size_t)r * D + col));
            __builtin_nontemporal_store(repv, reinterpret_cast<f4_t*>(out + (size_t)(r + 4) * D + col));
        }
        if (r < end) {
            __builtin_nontemporal_store(repv, reinterpret_cast<f4_t*>(out + (size_t)r * D + col));
        }
    }
}

extern "C" void kernel_launch(void* const* d_in, const int* in_sizes, int n_in,
                              void* d_out, int out_size, void* d_ws, size_t ws_size,
                              hipStream_t stream) {
    const float* emb = (const float*)d_in[0];
    const float* W   = (const float*)d_in[1];
    const int*   obj = (const int*)d_in[2];
    const int T = in_sizes[2];
    float* out = (float*)d_out;

    if (d_ws != nullptr && ws_size >= (size_t)(NSEG + 1) * sizeof(int)) {
        int* starts = (int*)d_ws;
        seg_starts_kernel<<<(T + 255) / 256, 256, 0, stream>>>(obj, T, starts);
        fused_seg_kernel<true><<<NSEG, 256, 0, stream>>>(emb, W, obj, T, starts, out);
    } else {
        fused_seg_kernel<false><<<NSEG, 256, 0, stream>>>(emb, W, obj, T, nullptr, out);
    }
}

// Round 2
// 909.629 us; speedup vs baseline: 1.0889x; 1.0339x over previous
//
#include <hip/hip_runtime.h>
#include <math.h>

#define D 256
#define NSEG 8192

typedef float f4_t __attribute__((ext_vector_type(4)));

// ---------- setup: segment starts (replaces per-block binary search) ----------
__global__ __launch_bounds__(256) void seg_starts_kernel(
        const int* __restrict__ obj, int T, int* __restrict__ starts) {
    const int i = blockIdx.x * blockDim.x + threadIdx.x;
    if (i >= T) return;
    const int cur  = obj[i];
    const int prev = (i == 0) ? -1 : obj[i - 1];
    for (int s = prev + 1; s <= cur; ++s) starts[s] = i;   // fills gaps (empty segs)
    if (i == T - 1) {
        for (int s = cur + 1; s <= NSEG; ++s) starts[s] = T;
    }
}

__device__ __forceinline__ int lower_bound_dev(const int* __restrict__ a, int n, int key) {
    int lo = 0, hi = n;
    while (lo < hi) {
        int mid = (lo + hi) >> 1;
        if (a[mid] < key) lo = mid + 1; else hi = mid;
    }
    return lo;
}

__device__ __forceinline__ float dot4(const float4 a, const float4 b) {
    return a.x * b.x + a.y * b.y + a.z * b.z + a.w * b.w;
}

__device__ __forceinline__ float4 ld4(const float* p) {
    return *reinterpret_cast<const float4*>(p);
}

// One block (256 threads = 4 waves) per segment. Fully fused:
//   pass 1: segment sum (HBM read, coalesced float4, FOUR loads in flight)
//   proj  : tg = tanh((s @ W) / cnt). wave w owns k-range [64w,64w+64),
//           lane owns 4 adjacent cols -> float4 W loads (1 KB/wave-instr)
//   pass 2: re-read rows (L2-hot), 4 rows/iter with interleaved shfl chains
//   pass 3: broadcast rep (nontemporal stores; out never re-read)
template <bool USE_STARTS>
__global__ __launch_bounds__(256) void fused_seg_kernel(
        const float* __restrict__ emb,
        const float* __restrict__ W,
        const int*   __restrict__ obj, int T,
        const int*   __restrict__ starts,
        float* __restrict__ out) {
    const int seg = blockIdx.x;
    int start, end;
    if (USE_STARTS) {
        start = starts[seg];          // uniform -> scalar loads
        end   = starts[seg + 1];
    } else {
        start = lower_bound_dev(obj, T, seg);
        end   = lower_bound_dev(obj, T, seg + 1);
    }
    if (start >= end) return;   // empty segment

    const int tid  = threadIdx.x;
    const int lane = tid & 63;
    const int w    = tid >> 6;
    const int col  = lane * 4;

    __shared__ float sm[4][D];   // cross-wave reduction scratch
    __shared__ float sv[D];      // segment sum
    __shared__ float tg[D];      // transformed global context

    const float* ebase = emb + col;

    // ---- pass 1: segment sum (4 loads in flight per wave) ----
    float4 acc = make_float4(0.f, 0.f, 0.f, 0.f);
    {
        int r = start + w;
        for (; r + 12 < end; r += 16) {
            const float4 e0 = ld4(ebase + (size_t)r * D);
            const float4 e1 = ld4(ebase + (size_t)(r + 4) * D);
            const float4 e2 = ld4(ebase + (size_t)(r + 8) * D);
            const float4 e3 = ld4(ebase + (size_t)(r + 12) * D);
            acc.x += (e0.x + e1.x) + (e2.x + e3.x);
            acc.y += (e0.y + e1.y) + (e2.y + e3.y);
            acc.z += (e0.z + e1.z) + (e2.z + e3.z);
            acc.w += (e0.w + e1.w) + (e2.w + e3.w);
        }
        for (; r < end; r += 4) {
            const float4 e0 = ld4(ebase + (size_t)r * D);
            acc.x += e0.x; acc.y += e0.y; acc.z += e0.z; acc.w += e0.w;
        }
    }
    *reinterpret_cast<float4*>(&sm[w][col]) = acc;
    __syncthreads();
    sv[tid] = sm[0][tid] + sm[1][tid] + sm[2][tid] + sm[3][tid];
    __syncthreads();

    // ---- projection: wave w handles k in [64w, 64w+64); lane handles
    //      columns [col, col+4) -> coalesced float4 row-slices of W.
    const float inv = 1.0f / (float)(end - start);
    float4 p4 = make_float4(0.f, 0.f, 0.f, 0.f);
    {
        const float* Wp = W + (size_t)(64 * w) * D + col;
        const float* svp = &sv[64 * w];
        #pragma unroll 8
        for (int kk = 0; kk < 64; ++kk) {
            const float  s  = svp[kk];                 // LDS broadcast (uniform)
            const float4 wr = ld4(Wp + (size_t)kk * D);
            p4.x += s * wr.x; p4.y += s * wr.y;
            p4.z += s * wr.z; p4.w += s * wr.w;
        }
    }
    // sm is free again (sv consumed it before the last barrier)
    *reinterpret_cast<float4*>(&sm[w][col]) = p4;
    __syncthreads();
    const float pj = sm[0][tid] + sm[1][tid] + sm[2][tid] + sm[3][tid];
    tg[tid] = tanhf(pj * inv);
    __syncthreads();
    const float4 tg4 = ld4(&tg[col]);

    // ---- pass 2: score + weighted sum (rows L2-hot), 4 rows/iter ----
    float4 racc = make_float4(0.f, 0.f, 0.f, 0.f);
    {
        int r = start + w;
        for (; r + 12 < end; r += 16) {
            const float4 e0 = ld4(ebase + (size_t)r * D);
            const float4 e1 = ld4(ebase + (size_t)(r + 4) * D);
            const float4 e2 = ld4(ebase + (size_t)(r + 8) * D);
            const float4 e3 = ld4(ebase + (size_t)(r + 12) * D);
            float pd0 = dot4(e0, tg4);
            float pd1 = dot4(e1, tg4);
            float pd2 = dot4(e2, tg4);
            float pd3 = dot4(e3, tg4);
            #pragma unroll
            for (int off = 32; off >= 1; off >>= 1) {   // 4 chains interleaved
                pd0 += __shfl_xor(pd0, off, 64);
                pd1 += __shfl_xor(pd1, off, 64);
                pd2 += __shfl_xor(pd2, off, 64);
                pd3 += __shfl_xor(pd3, off, 64);
            }
            const float s0 = 1.0f / (1.0f + __expf(-pd0));
            const float s1 = 1.0f / (1.0f + __expf(-pd1));
            const float s2 = 1.0f / (1.0f + __expf(-pd2));
            const float s3 = 1.0f / (1.0f + __expf(-pd3));
            racc.x += (e0.x * s0 + e1.x * s1) + (e2.x * s2 + e3.x * s3);
            racc.y += (e0.y * s0 + e1.y * s1) + (e2.y * s2 + e3.y * s3);
            racc.z += (e0.z * s0 + e1.z * s1) + (e2.z * s2 + e3.z * s3);
            racc.w += (e0.w * s0 + e1.w * s1) + (e2.w * s2 + e3.w * s3);
        }
        for (; r < end; r += 4) {
            const float4 e0 = ld4(ebase + (size_t)r * D);
            float pd0 = dot4(e0, tg4);
            #pragma unroll
            for (int off = 32; off >= 1; off >>= 1) pd0 += __shfl_xor(pd0, off, 64);
            const float s0 = 1.0f / (1.0f + __expf(-pd0));
            racc.x += e0.x * s0; racc.y += e0.y * s0;
            racc.z += e0.z * s0; racc.w += e0.w * s0;
        }
    }
    *reinterpret_cast<float4*>(&sm[w][col]) = racc;
    __syncthreads();
    sm[0][tid] = sm[0][tid] + sm[1][tid] + sm[2][tid] + sm[3][tid];
    __syncthreads();
    const float4 rep4 = ld4(&sm[0][col]);
    const f4_t repv = { rep4.x, rep4.y, rep4.z, rep4.w };

    // ---- pass 3: broadcast rep to every token row (nontemporal) ----
    {
        float* obase = out + col;
        int r = start + w;
        for (; r + 12 < end; r += 16) {
            __builtin_nontemporal_store(repv, reinterpret_cast<f4_t*>(obase + (size_t)r * D));
            __builtin_nontemporal_store(repv, reinterpret_cast<f4_t*>(obase + (size_t)(r + 4) * D));
            __builtin_nontemporal_store(repv, reinterpret_cast<f4_t*>(obase + (size_t)(r + 8) * D));
            __builtin_nontemporal_store(repv, reinterpret_cast<f4_t*>(obase + (size_t)(r + 12) * D));
        }
        for (; r < end; r += 4) {
            __builtin_nontemporal_store(repv, reinterpret_cast<f4_t*>(obase + (size_t)r * D));
        }
    }
}

extern "C" void kernel_launch(void* const* d_in, const int* in_sizes, int n_in,
                              void* d_out, int out_size, void* d_ws, size_t ws_size,
                              hipStream_t stream) {
    const float* emb = (const float*)d_in[0];
    const float* W   = (const float*)d_in[1];
    const int*   obj = (const int*)d_in[2];
    const int T = in_sizes[2];
    float* out = (float*)d_out;

    if (d_ws != nullptr && ws_size >= (size_t)(NSEG + 1) * sizeof(int)) {
        int* starts = (int*)d_ws;
        seg_starts_kernel<<<(T + 255) / 256, 256, 0, stream>>>(obj, T, starts);
        fused_seg_kernel<true><<<NSEG, 256, 0, stream>>>(emb, W, obj, T, starts, out);
    } else {
        fused_seg_kernel<false><<<NSEG, 256, 0, stream>>>(emb, W, obj, T, nullptr, out);
    }
}